// Round 13
// baseline (19.874 us; speedup 1.0000x reference)
//
#include <hip/hip_runtime.h>

#define EMBED 512
#define NTOK 8192
#define MT 32            // tokens per block (two 16-row MFMA M-tiles)
#define NB1 6            // GEMM1 N-frags (96 cols = 16 fc1w^T | 64 W1 | 4 b1 | pad)
#define KS1 16           // GEMM1 K-steps (512/32)
#define NB2 32           // GEMM2 N-frags (512 cols)
#define KS2 3            // GEMM2 K-steps (96/32; rows 68..95 zero)
#define B1HALVES (KS1 * NB1 * 64 * 8)   // 49152 halves = 96 KB
#define XR 520           // x LDS pitch (halves)
#define ZR 104           // z LDS pitch (halves)

using half8   = __attribute__((ext_vector_type(8))) _Float16;
using half2_t = __attribute__((ext_vector_type(2))) _Float16;
using f32x4   = __attribute__((ext_vector_type(4))) float;

#define MFMA16(a, b, c) __builtin_amdgcn_mfma_f32_16x16x32_f16((a), (b), (c), 0, 0, 0)

__device__ __forceinline__ unsigned pkrtz_u(float a, float b) {
    return __builtin_bit_cast(unsigned, __builtin_amdgcn_cvt_pkrtz(a, b));
}
__device__ __forceinline__ half2_t pkrtz(float a, float b) {
    return __builtin_bit_cast(half2_t, __builtin_amdgcn_cvt_pkrtz(a, b));
}

// ---------------------------------------------------------------------------
// ONE kernel, no prep, no workspace. MT=32 tokens/block, 256 blocks, 8 waves.
// Per block: issue x loads; pack B1 panel (frag order) into LDS from RAW
// weights (coalesced reads + scalar LDS scatter); x->f16 LDS; GEMM1(LDS);
// b2 frags in-register from raw (R11-validated); glue; GEMM2; store.
// Frag convention: slot halves ((ks*NB1+nf)*64+lane)*8+i holds
//   B[k = ks*32 + (lane>>4)*8 + i][col = nf*16 + (lane&15)].
// ---------------------------------------------------------------------------
__global__ __launch_bounds__(512, 2) void hyper(const float* __restrict__ x,
                                                const float* __restrict__ fc1w,
                                                const float* __restrict__ fc1b,
                                                const float* __restrict__ fc2w,
                                                const float* __restrict__ fc2b,
                                                float* __restrict__ out)
{
    __shared__ _Float16 b1lds[B1HALVES];    // 96 KB
    __shared__ _Float16 xh[MT][XR];         // 33.3 KB
    __shared__ float    c1s[MT][100];       // 12.8 KB
    __shared__ _Float16 zh[MT][ZR];         // 6.7 KB  -> 147.5 KB total

    const int tid  = threadIdx.x;
    const int lane = tid & 63;
    const int wv   = tid >> 6;              // 0..7
    const int rowA = lane & 15;
    const int kgrp = lane >> 4;             // 0..3
    const long tok0 = (long)blockIdx.x * MT;

    // ---- issue x loads (64 KB HBM/L3), latency hides under B1 pack ----------
    float4 xr[8];
    {
        const float4* xg = reinterpret_cast<const float4*>(x + tok0 * EMBED);
        #pragma unroll
        for (int i = 0; i < 8; ++i) xr[i] = xg[tid + i * 512];
    }

    // ---- pack B1 cols 16-79 (W1): thread slot -> one row (e,j), 16 k's ------
    #pragma unroll
    for (int it = 0; it < 4; ++it) {
        const int slot = it * 512 + tid;               // 2048 slots
        const int i  = slot & 7;
        const int lh = (slot >> 3) & 3;
        const int j  = (slot >> 5) & 3;
        const int ks = slot >> 7;                      // 0..15
        const int e  = ks * 32 + lh * 8 + i;
        const float4* p = reinterpret_cast<const float4*>(fc2w + e * 64 + j * 16);
        float4 v0 = p[0], v1 = p[1], v2 = p[2], v3 = p[3];
        const float vv[16] = {v0.x,v0.y,v0.z,v0.w, v1.x,v1.y,v1.z,v1.w,
                              v2.x,v2.y,v2.z,v2.w, v3.x,v3.y,v3.z,v3.w};
        const int base = ((ks * NB1 + 1 + j) * 64 + lh * 16) * 8 + i;
        #pragma unroll
        for (int k = 0; k < 16; ++k) b1lds[base + k * 8] = (_Float16)vv[k];
    }
    // ---- pack B1 cols 0-15 (fc1w^T): contiguous reads, b128 writes ----------
    {
        const int c  = tid >> 5;                       // 0..15
        const int e0 = (tid & 31) * 16;
        const int ks = e0 >> 5;
        const float4* p = reinterpret_cast<const float4*>(fc1w + c * EMBED + e0);
        float4 v0 = p[0], v1 = p[1], v2 = p[2], v3 = p[3];
        const float vv[16] = {v0.x,v0.y,v0.z,v0.w, v1.x,v1.y,v1.z,v1.w,
                              v2.x,v2.y,v2.z,v2.w, v3.x,v3.y,v3.z,v3.w};
        #pragma unroll
        for (int g = 0; g < 2; ++g) {
            const int lh = ((e0 & 31) >> 3) + g;       // {0,1} or {2,3}
            half8 h;
            #pragma unroll
            for (int m = 0; m < 8; ++m) h[m] = (_Float16)vv[g * 8 + m];
            *reinterpret_cast<half8*>(&b1lds[((ks * NB1 + 0) * 64 + lh * 16 + c) * 8]) = h;
        }
    }
    // ---- pack B1 cols 80-95 (b1 bias | zero), frag nf=5 ---------------------
    {
        const int i  = tid & 7;
        const int lh = (tid >> 3) & 3;
        const int ks = tid >> 5;                       // 0..15
        const int e  = ks * 32 + lh * 8 + i;
        const float4 b4 = *reinterpret_cast<const float4*>(fc2b + e * 4);
        const int base = ((ks * NB1 + 5) * 64 + lh * 16) * 8 + i;
        #pragma unroll
        for (int k = 0; k < 16; ++k) {
            const float v = (k == 0) ? b4.x : (k == 1) ? b4.y :
                            (k == 2) ? b4.z : (k == 3) ? b4.w : 0.f;
            b1lds[base + k * 8] = (_Float16)v;
        }
    }

    // ---- x regs -> f16 LDS --------------------------------------------------
    #pragma unroll
    for (int i = 0; i < 8; ++i) {
        const int idx = tid + i * 512;                 // 4096 float4
        const int t = idx >> 7, e4 = idx & 127;
        uint2 w;
        w.x = pkrtz_u(xr[i].x, xr[i].y);
        w.y = pkrtz_u(xr[i].z, xr[i].w);
        *reinterpret_cast<uint2*>(&xh[t][e4 * 4]) = w;
    }
    __syncthreads();

    // ================= GEMM1: X[32x512] * B1[512x96] (waves 0-5) =============
    if (wv < 6) {
        const int nfp = wv >> 1, mt = wv & 1;
        const int nf0 = nfp * 2, nf1 = nf0 + 1;
        f32x4 accA = {0.f, 0.f, 0.f, 0.f};
        f32x4 accB = {0.f, 0.f, 0.f, 0.f};
        #pragma unroll
        for (int ks = 0; ks < KS1; ++ks) {
            half8 a   = *reinterpret_cast<const half8*>(&xh[mt * 16 + rowA][ks * 32 + kgrp * 8]);
            half8 b0  = *reinterpret_cast<const half8*>(&b1lds[((ks * NB1 + nf0) * 64 + lane) * 8]);
            half8 b1v = *reinterpret_cast<const half8*>(&b1lds[((ks * NB1 + nf1) * 64 + lane) * 8]);
            accA = MFMA16(a, b0, accA);
            accB = MFMA16(a, b1v, accB);
        }
        #pragma unroll
        for (int r = 0; r < 4; ++r) {
            c1s[mt * 16 + kgrp * 4 + r][nf0 * 16 + rowA] = accA[r];
            c1s[mt * 16 + kgrp * 4 + r][nf1 * 16 + rowA] = accB[r];
        }
    }

    // ---- b2 frags in-register from RAW layout (R11-validated) ---------------
    half8 b2r[KS2][4];
    #pragma unroll
    for (int f = 0; f < 4; ++f) {
        const int e = (wv * 4 + f) * 16 + rowA;
        #pragma unroll
        for (int ks = 0; ks < 2; ++ks) {
            const int k0 = ks * 32 + kgrp * 8;         // k0&15 in {0,8}
            const float4* p = reinterpret_cast<const float4*>(
                fc2w + (long)(2048 + (k0 >> 4) * 512 + e) * 16 + (k0 & 15));
            float4 a = p[0], b = p[1];
            const float v[8] = {a.x, a.y, a.z, a.w, b.x, b.y, b.z, b.w};
            half8 h;
            #pragma unroll
            for (int i = 0; i < 8; ++i) h[i] = (_Float16)v[i];
            b2r[ks][f] = h;
        }
        {
            half8 h;
            #pragma unroll
            for (int i = 0; i < 8; ++i) {
                const int krow = 64 + kgrp * 8 + i;
                h[i] = (_Float16)((krow < 68) ? fc2b[2048 + (krow - 64) * 512 + e] : 0.f);
            }
            b2r[2][f] = h;
        }
    }
    __syncthreads();

    // ================= glue (tid<128): h, y1, Z = (y1 (x) h | y1 | 0) ========
    if (tid < 128) {
        const int t = tid >> 2, j = tid & 3;
        float h[16];
        #pragma unroll
        for (int k = 0; k < 16; ++k) h[k] = fmaxf(c1s[t][k] + fc1b[k], 0.f);
        float y1 = c1s[t][80 + j];
        #pragma unroll
        for (int k = 0; k < 16; ++k) y1 = fmaf(c1s[t][16 + j * 16 + k], h[k], y1);
        y1 = fmaxf(y1, 0.f);
        #pragma unroll
        for (int k = 0; k < 16; k += 2) {
            half2_t p = pkrtz(y1 * h[k], y1 * h[k + 1]);
            *reinterpret_cast<half2_t*>(&zh[t][j * 16 + k]) = p;
        }
        zh[t][64 + j] = (_Float16)y1;
        #pragma unroll
        for (int p = 0; p < 7; ++p) zh[t][68 + j * 7 + p] = (_Float16)0.f;
    }
    __syncthreads();

    // ================= GEMM2: Z[32x96] * B2[96x512], 2 M-tiles/wave ==========
    f32x4 acc20[4], acc21[4];
    #pragma unroll
    for (int f = 0; f < 4; ++f) {
        acc20[f] = (f32x4){0.f, 0.f, 0.f, 0.f};
        acc21[f] = (f32x4){0.f, 0.f, 0.f, 0.f};
    }
    #pragma unroll
    for (int ks = 0; ks < KS2; ++ks) {
        half8 az0 = *reinterpret_cast<const half8*>(&zh[rowA][ks * 32 + kgrp * 8]);
        half8 az1 = *reinterpret_cast<const half8*>(&zh[16 + rowA][ks * 32 + kgrp * 8]);
        #pragma unroll
        for (int f = 0; f < 4; ++f) {
            acc20[f] = MFMA16(az0, b2r[ks][f], acc20[f]);
            acc21[f] = MFMA16(az1, b2r[ks][f], acc21[f]);
        }
    }

    // ================= relu + store ==========================================
    #pragma unroll
    for (int f = 0; f < 4; ++f) {
        const int e = (wv * 4 + f) * 16 + rowA;
        #pragma unroll
        for (int r = 0; r < 4; ++r) {
            out[(tok0 + kgrp * 4 + r) * EMBED + e]      = fmaxf(acc20[f][r], 0.f);
            out[(tok0 + 16 + kgrp * 4 + r) * EMBED + e] = fmaxf(acc21[f][r], 0.f);
        }
    }
}

extern "C" void kernel_launch(void* const* d_in, const int* in_sizes, int n_in,
                              void* d_out, int out_size, void* d_ws, size_t ws_size,
                              hipStream_t stream) {
    const float* x    = (const float*)d_in[0];
    const float* fc1w = (const float*)d_in[1];
    const float* fc1b = (const float*)d_in[2];
    const float* fc2w = (const float*)d_in[3];
    const float* fc2b = (const float*)d_in[4];
    float* out = (float*)d_out;

    hyper<<<dim3(NTOK / MT), dim3(512), 0, stream>>>(x, fc1w, fc1b, fc2w, fc2b, out);
}